// Round 4
// baseline (720.766 us; speedup 1.0000x reference)
//
#include <hip/hip_runtime.h>
#include <hip/hip_bf16.h>

#define N_PAPER 30000
#define N_AUTHOR 20000
#define N_NODES 50000
#define N_EDGES 800000
#define D_PAPER 512
#define D_AUTHOR 256
#define N_HID 128
#define N_OUT 64
#define HEADS 2
#define NEG_SLOPE 0.2f

typedef short s16x8 __attribute__((ext_vector_type(8)));
typedef float f32x4 __attribute__((ext_vector_type(4)));
typedef unsigned short ushort_t;

__device__ __forceinline__ unsigned short f2b(float x) {
    unsigned u = __float_as_uint(x);
    u += 0x7fffu + ((u >> 16) & 1u);   // RNE
    return (unsigned short)(u >> 16);
}
__device__ __forceinline__ float b2f(unsigned short h) {
    return __uint_as_float(((unsigned)h) << 16);
}
__device__ __forceinline__ float lrelu(float x) {
    return (x > 0.f) ? x : NEG_SLOPE * x;
}

// ---------------- fused W pre-split+transpose for all 4 weight matrices ----------------
__device__ __forceinline__ void wsplit1(const float* __restrict__ W, ushort_t* __restrict__ WTh,
                                        ushort_t* __restrict__ WTl, int K, int NOUT, int idx) {
    int k = idx / NOUT, c = idx % NOUT;
    float x = W[idx];
    unsigned short h = f2b(x);
    float r = x - b2f(h);
    WTh[c * K + k] = h;
    WTl[c * K + k] = f2b(r);
}

__global__ __launch_bounds__(256) void wsplit_all(
        const float* __restrict__ W1p, const float* __restrict__ W1a,
        const float* __restrict__ Wg1, const float* __restrict__ Wg2,
        ushort_t* wt1ph, ushort_t* wt1pl, ushort_t* wt1ah, ushort_t* wt1al,
        ushort_t* wtg1h, ushort_t* wtg1l, ushort_t* wtg2h, ushort_t* wtg2l) {
    int i = blockIdx.x * 256 + threadIdx.x;
    if (i < 65536)       wsplit1(W1p, wt1ph, wt1pl, D_PAPER, N_HID, i);
    else if (i < 98304)  wsplit1(W1a, wt1ah, wt1al, D_AUTHOR, N_HID, i - 65536);
    else if (i < 131072) wsplit1(Wg1, wtg1h, wtg1l, N_HID, 2 * N_HID, i - 98304);
    else if (i < 147456) wsplit1(Wg2, wtg2h, wtg2l, 2 * N_HID, N_OUT, i - 131072);
}

// ---------------- split-bf16 MFMA GEMM ----------------
// MODE 0: A fp32; out = split bf16 (hi,lo); +bias +relu     (encoders)
// MODE 1: A split bf16; out = bf16; fused alpha (2 heads)   (GAT1 transform)
// MODE 2: A split bf16; out = bf16; fused alpha (1 head)    (GAT2 transform)
template<int NOUT, int MODE>
__global__ __launch_bounds__(256) void gemm_mfma_kernel(
        const void* __restrict__ Av, const ushort_t* __restrict__ Al,
        const ushort_t* __restrict__ WTh, const ushort_t* __restrict__ WTl,
        const float* __restrict__ bias,
        const float* __restrict__ asrc, const float* __restrict__ adst,
        ushort_t* __restrict__ outH, ushort_t* __restrict__ outL,
        float* __restrict__ as_o, float* __restrict__ ad_o, int M, int K) {
    constexpr int NF = NOUT / 16;
    const int tid = threadIdx.x;
    const int wid = tid >> 6, lane = tid & 63;
    const int l16 = lane & 15, kg = lane >> 4;
    const int arow = blockIdx.x * 64 + wid * 16 + l16;
    const bool avalid = arow < M;
    const int arow_s = avalid ? arow : 0;
    const ushort_t* wph = WTh + (size_t)l16 * K + kg * 8;
    const ushort_t* wpl = WTl + (size_t)l16 * K + kg * 8;

    f32x4 acc[NF];
#pragma unroll
    for (int f = 0; f < NF; f++)
#pragma unroll
        for (int e = 0; e < 4; e++) acc[f][e] = 0.f;

    for (int k0 = 0; k0 < K; k0 += 32) {
        s16x8 ah, al;
        if (MODE == 0) {
            const float* ap = (const float*)Av + (size_t)arow_s * K + kg * 8 + k0;
            float4 u0 = *reinterpret_cast<const float4*>(ap);
            float4 u1 = *reinterpret_cast<const float4*>(ap + 4);
            float av[8] = {u0.x, u0.y, u0.z, u0.w, u1.x, u1.y, u1.z, u1.w};
#pragma unroll
            for (int i = 0; i < 8; i++) {
                unsigned short h = f2b(av[i]);
                ah[i] = (short)h;
                al[i] = (short)f2b(av[i] - b2f(h));
            }
        } else {
            const ushort_t* aph = (const ushort_t*)Av + (size_t)arow_s * K + kg * 8 + k0;
            const ushort_t* apl = Al + (size_t)arow_s * K + kg * 8 + k0;
            ah = *reinterpret_cast<const s16x8*>(aph);
            al = *reinterpret_cast<const s16x8*>(apl);
        }
#pragma unroll
        for (int f = 0; f < NF; f++) {
            const size_t wo = (size_t)f * 16 * K + k0;
            s16x8 bh = *reinterpret_cast<const s16x8*>(wph + wo);
            s16x8 bl = *reinterpret_cast<const s16x8*>(wpl + wo);
            acc[f] = __builtin_amdgcn_mfma_f32_16x16x32_bf16(al, bh, acc[f], 0, 0, 0);
            acc[f] = __builtin_amdgcn_mfma_f32_16x16x32_bf16(ah, bl, acc[f], 0, 0, 0);
            acc[f] = __builtin_amdgcn_mfma_f32_16x16x32_bf16(ah, bh, acc[f], 0, 0, 0);
        }
    }

    const int orow0 = blockIdx.x * 64 + wid * 16 + kg * 4;

    // ---- store ----
#pragma unroll
    for (int f = 0; f < NF; f++) {
        const int col = f * 16 + l16;
        const float bv = (MODE == 0) ? bias[col] : 0.f;
#pragma unroll
        for (int r = 0; r < 4; r++) {
            const int gr = orow0 + r;
            if (gr >= M) continue;
            float v = acc[f][r] + bv;
            if (MODE == 0) {
                v = fmaxf(v, 0.f);
                unsigned short h = f2b(v);
                outH[(size_t)gr * NOUT + col] = h;
                outL[(size_t)gr * NOUT + col] = f2b(v - b2f(h));
            } else {
                outH[(size_t)gr * NOUT + col] = f2b(v);
            }
        }
    }

    // ---- fused alpha dot products ----
    if (MODE == 1) {
        float sA[2][4] = {{0.f,0.f,0.f,0.f},{0.f,0.f,0.f,0.f}};
        float dA[2][4] = {{0.f,0.f,0.f,0.f},{0.f,0.f,0.f,0.f}};
#pragma unroll
        for (int f = 0; f < NF; f++) {
            const int head = f >> 3;
            const int cc = (f & 7) * 16 + l16;
            const float avs = asrc[head * 128 + cc];
            const float avd = adst[head * 128 + cc];
#pragma unroll
            for (int r = 0; r < 4; r++) {
                sA[head][r] += acc[f][r] * avs;
                dA[head][r] += acc[f][r] * avd;
            }
        }
#pragma unroll
        for (int m = 1; m < 16; m <<= 1) {
#pragma unroll
            for (int h = 0; h < 2; h++)
#pragma unroll
                for (int r = 0; r < 4; r++) {
                    sA[h][r] += __shfl_xor(sA[h][r], m);
                    dA[h][r] += __shfl_xor(dA[h][r], m);
                }
        }
        if (l16 == 0) {
#pragma unroll
            for (int r = 0; r < 4; r++) {
                const int row = orow0 + r;
                if (row < M) {
                    as_o[row * 2 + 0] = sA[0][r];
                    as_o[row * 2 + 1] = sA[1][r];
                    ad_o[row * 2 + 0] = dA[0][r];
                    ad_o[row * 2 + 1] = dA[1][r];
                }
            }
        }
    } else if (MODE == 2) {
        float sA[4] = {0.f,0.f,0.f,0.f};
        float dA[4] = {0.f,0.f,0.f,0.f};
#pragma unroll
        for (int f = 0; f < NF; f++) {
            const int cc = f * 16 + l16;
            const float avs = asrc[cc];
            const float avd = adst[cc];
#pragma unroll
            for (int r = 0; r < 4; r++) {
                sA[r] += acc[f][r] * avs;
                dA[r] += acc[f][r] * avd;
            }
        }
#pragma unroll
        for (int m = 1; m < 16; m <<= 1) {
#pragma unroll
            for (int r = 0; r < 4; r++) {
                sA[r] += __shfl_xor(sA[r], m);
                dA[r] += __shfl_xor(dA[r], m);
            }
        }
        if (l16 == 0) {
#pragma unroll
            for (int r = 0; r < 4; r++) {
                const int row = orow0 + r;
                if (row < M) {
                    as_o[row] = sA[r];
                    ad_o[row] = dA[r];
                }
            }
        }
    }
}

// ---------------- CSR build ----------------
__global__ void deg_kernel(const int* __restrict__ dst, int* __restrict__ deg) {
    int e = blockIdx.x * blockDim.x + threadIdx.x;
    if (e < N_EDGES) atomicAdd(&deg[dst[e]], 1);
}

__global__ __launch_bounds__(1024) void scan_kernel(const int* __restrict__ deg,
                                                    int* __restrict__ rowoff,
                                                    int* __restrict__ cursor) {
    __shared__ int tmp[1024];
    const int tid = threadIdx.x;
    constexpr int CH = (N_NODES + 1023) / 1024;
    const int t0 = tid * CH;
    int s = 0;
    for (int i = 0; i < CH; i++) {
        int idx = t0 + i;
        if (idx < N_NODES) s += deg[idx];
    }
    tmp[tid] = s;
    __syncthreads();
    for (int off = 1; off < 1024; off <<= 1) {
        int t = (tid >= off) ? tmp[tid - off] : 0;
        __syncthreads();
        tmp[tid] += t;
        __syncthreads();
    }
    int run = tmp[tid] - s;
    for (int i = 0; i < CH; i++) {
        int idx = t0 + i;
        if (idx < N_NODES) {
            rowoff[idx] = run;
            cursor[idx] = run;
            run += deg[idx];
        }
    }
    if (tid == 1023) rowoff[N_NODES] = tmp[1023];
}

__global__ void scatter_kernel(const int* __restrict__ src, const int* __restrict__ dst,
                               int* __restrict__ cursor, int* __restrict__ csr_src) {
    int e = blockIdx.x * blockDim.x + threadIdx.x;
    if (e >= N_EDGES) return;
    int d = dst[e];
    int pos = atomicAdd(&cursor[d], 1);
    csr_src[pos] = src[e];
}

// ---------------- layer-1 aggregation ----------------
// block = 256 threads / node; thread owns channel pair (2*c2, 2*c2+1); halves split edges.
__global__ __launch_bounds__(256) void agg1_kernel(
        const int* __restrict__ rowoff, const int* __restrict__ csr,
        const float* __restrict__ as_, const float* __restrict__ ad_,
        const ushort_t* __restrict__ hb, const float* __restrict__ bias,
        ushort_t* __restrict__ x2h, ushort_t* __restrict__ x2l) {
    const int n = blockIdx.x;
    const int tid = threadIdx.x;
    const int c2 = tid & 127;
    const int half = tid >> 7;
    const int head = c2 >> 6;
    __shared__ int s_src[256];
    __shared__ float s_w[2][256];
    __shared__ float s_red[128][3];

    const float adv0 = ad_[n * 2], adv1 = ad_[n * 2 + 1];
    const int r0 = rowoff[n], r1 = rowoff[n + 1];
    float acc0 = 0.f, acc1 = 0.f, wsum = 0.f;

    for (int base = r0; base < r1; base += 256) {
        const int cnt = min(256, r1 - base);
        __syncthreads();
        if (tid < cnt) {
            int s = csr[base + tid];
            s_src[tid] = s;
            s_w[0][tid] = __expf(lrelu(as_[s * 2 + 0] + adv0));
            s_w[1][tid] = __expf(lrelu(as_[s * 2 + 1] + adv1));
        }
        __syncthreads();
#pragma unroll 4
        for (int jj = 0; jj < cnt; jj += 2) {
            const int j = jj + half;
            if (j < cnt) {
                const float w = s_w[head][j];
                const unsigned v = *reinterpret_cast<const unsigned*>(
                    hb + (size_t)s_src[j] * 256 + 2 * c2);
                acc0 += b2f((unsigned short)(v & 0xffffu)) * w;
                acc1 += b2f((unsigned short)(v >> 16)) * w;
                wsum += w;
            }
        }
    }
    __syncthreads();
    if (half == 1) {
        s_red[c2][0] = acc0;
        s_red[c2][1] = acc1;
        s_red[c2][2] = wsum;
    }
    __syncthreads();
    if (half == 0) {
        acc0 += s_red[c2][0];
        acc1 += s_red[c2][1];
        wsum += s_red[c2][2];
        const float inv = 1.f / (wsum + 1e-16f);
        const float2 bv = *reinterpret_cast<const float2*>(bias + 2 * c2);
        float o0 = acc0 * inv + bv.x;
        float o1 = acc1 * inv + bv.y;
        o0 = (o0 > 0.f) ? o0 : (__expf(o0) - 1.f);
        o1 = (o1 > 0.f) ? o1 : (__expf(o1) - 1.f);
        ushort2 hh, ll;
        hh.x = f2b(o0); ll.x = f2b(o0 - b2f(hh.x));
        hh.y = f2b(o1); ll.y = f2b(o1 - b2f(hh.y));
        *reinterpret_cast<ushort2*>(x2h + (size_t)n * 256 + 2 * c2) = hh;
        *reinterpret_cast<ushort2*>(x2l + (size_t)n * 256 + 2 * c2) = ll;
    }
}

// ---------------- layer-2 aggregation: wave per node, bf16 gather, ch-pair + halves ----
__global__ __launch_bounds__(256) void agg2_kernel(
        const int* __restrict__ rowoff, const int* __restrict__ csr,
        const float* __restrict__ as_, const float* __restrict__ ad_,
        const ushort_t* __restrict__ h2b, const float* __restrict__ bias,
        float* __restrict__ out) {
    const int wid = threadIdx.x >> 6, lane = threadIdx.x & 63;
    const int n = blockIdx.x * 4 + wid;
    if (n >= N_NODES) return;
    const int c2 = lane & 31;
    const int half = lane >> 5;
    const float adv = ad_[n];
    const int r0 = rowoff[n], r1 = rowoff[n + 1];
    float acc0 = 0.f, acc1 = 0.f, wsum = 0.f;

    for (int base = r0; base < r1; base += 64) {
        const int cnt = min(64, r1 - base);
        int s = 0;
        float w = 0.f;
        if (lane < cnt) {
            s = csr[base + lane];
            w = __expf(lrelu(as_[s] + adv));
        }
        const int half_rounds = (cnt + 1) >> 1;
#pragma unroll 4
        for (int jj = 0; jj < half_rounds; jj++) {
            const int j = jj * 2 + half;
            const int sb = __shfl(s, j);
            const float wb = __shfl(w, j);
            if (j < cnt) {
                const unsigned v = *reinterpret_cast<const unsigned*>(
                    h2b + (size_t)sb * 64 + 2 * c2);
                acc0 += b2f((unsigned short)(v & 0xffffu)) * wb;
                acc1 += b2f((unsigned short)(v >> 16)) * wb;
                wsum += wb;
            }
        }
    }
    acc0 += __shfl_xor(acc0, 32);
    acc1 += __shfl_xor(acc1, 32);
    wsum += __shfl_xor(wsum, 32);
    if (half == 0) {
        const float inv = 1.f / (wsum + 1e-16f);
        float2 o;
        o.x = acc0 * inv + bias[2 * c2];
        o.y = acc1 * inv + bias[2 * c2 + 1];
        *reinterpret_cast<float2*>(out + (size_t)n * 64 + 2 * c2) = o;
    }
}

// ---------------- launch ----------------
extern "C" void kernel_launch(void* const* d_in, const int* in_sizes, int n_in,
                              void* d_out, int out_size, void* d_ws, size_t ws_size,
                              hipStream_t stream) {
    const float* x_paper  = (const float*)d_in[0];
    const float* x_author = (const float*)d_in[1];
    const int*   edge_idx = (const int*)d_in[2];
    const float* W1p = (const float*)d_in[3];
    const float* b1p = (const float*)d_in[4];
    const float* W1a = (const float*)d_in[5];
    const float* b1a = (const float*)d_in[6];
    const float* Wg1 = (const float*)d_in[7];
    const float* asrc1 = (const float*)d_in[8];
    const float* adst1 = (const float*)d_in[9];
    const float* bg1 = (const float*)d_in[10];
    const float* Wg2 = (const float*)d_in[11];
    const float* asrc2 = (const float*)d_in[12];
    const float* adst2 = (const float*)d_in[13];
    const float* bg2 = (const float*)d_in[14];
    float* out = (float*)d_out;

    const int* src = edge_idx;
    const int* dst = edge_idx + N_EDGES;

    char* ws = (char*)d_ws;
    size_t off = 0;
    auto alloc = [&](size_t bytes) -> void* {
        void* p = ws + off;
        off += (bytes + 255) & ~(size_t)255;
        return p;
    };
    ushort_t* xh    = (ushort_t*)alloc((size_t)N_NODES * N_HID * 2);
    ushort_t* xl    = (ushort_t*)alloc((size_t)N_NODES * N_HID * 2);
    ushort_t* h1b   = (ushort_t*)alloc((size_t)N_NODES * 2 * N_HID * 2);
    ushort_t* x2h   = (ushort_t*)alloc((size_t)N_NODES * 2 * N_HID * 2);
    ushort_t* x2l   = (ushort_t*)alloc((size_t)N_NODES * 2 * N_HID * 2);
    ushort_t* h2b   = (ushort_t*)alloc((size_t)N_NODES * N_OUT * 2);
    ushort_t* wt1ph = (ushort_t*)alloc((size_t)D_PAPER * N_HID * 2);
    ushort_t* wt1pl = (ushort_t*)alloc((size_t)D_PAPER * N_HID * 2);
    ushort_t* wt1ah = (ushort_t*)alloc((size_t)D_AUTHOR * N_HID * 2);
    ushort_t* wt1al = (ushort_t*)alloc((size_t)D_AUTHOR * N_HID * 2);
    ushort_t* wtg1h = (ushort_t*)alloc((size_t)N_HID * 2 * N_HID * 2);
    ushort_t* wtg1l = (ushort_t*)alloc((size_t)N_HID * 2 * N_HID * 2);
    ushort_t* wtg2h = (ushort_t*)alloc((size_t)2 * N_HID * N_OUT * 2);
    ushort_t* wtg2l = (ushort_t*)alloc((size_t)2 * N_HID * N_OUT * 2);
    float*    as1   = (float*)alloc((size_t)N_NODES * HEADS * 4);
    float*    ad1   = (float*)alloc((size_t)N_NODES * HEADS * 4);
    float*    as2   = (float*)alloc((size_t)N_NODES * 4);
    float*    ad2   = (float*)alloc((size_t)N_NODES * 4);
    int*      deg    = (int*)alloc((size_t)N_NODES * 4);
    int*      rowoff = (int*)alloc((size_t)(N_NODES + 1) * 4);
    int*      cursor = (int*)alloc((size_t)N_NODES * 4);
    int*      csrsrc = (int*)alloc((size_t)N_EDGES * 4);

    const int EB = (N_EDGES + 255) / 256;

    // --- W pre-split/transpose (single fused launch) ---
    wsplit_all<<<576, 256, 0, stream>>>(W1p, W1a, Wg1, Wg2,
        wt1ph, wt1pl, wt1ah, wt1al, wtg1h, wtg1l, wtg2h, wtg2l);

    // --- CSR build ---
    hipMemsetAsync(deg, 0, N_NODES * 4, stream);
    deg_kernel<<<EB, 256, 0, stream>>>(dst, deg);
    scan_kernel<<<1, 1024, 0, stream>>>(deg, rowoff, cursor);
    scatter_kernel<<<EB, 256, 0, stream>>>(src, dst, cursor, csrsrc);

    // --- encoders: fp32 in, split-bf16 out ---
    gemm_mfma_kernel<N_HID, 0><<<(N_PAPER + 63) / 64, 256, 0, stream>>>(
        x_paper, nullptr, wt1ph, wt1pl, b1p, nullptr, nullptr,
        xh, xl, nullptr, nullptr, N_PAPER, D_PAPER);
    gemm_mfma_kernel<N_HID, 0><<<(N_AUTHOR + 63) / 64, 256, 0, stream>>>(
        x_author, nullptr, wt1ah, wt1al, b1a, nullptr, nullptr,
        xh + (size_t)N_PAPER * N_HID, xl + (size_t)N_PAPER * N_HID,
        nullptr, nullptr, N_AUTHOR, D_AUTHOR);

    // --- GAT layer 1: transform + fused alpha ---
    gemm_mfma_kernel<2 * N_HID, 1><<<(N_NODES + 63) / 64, 256, 0, stream>>>(
        xh, xl, wtg1h, wtg1l, nullptr, asrc1, adst1,
        h1b, nullptr, as1, ad1, N_NODES, N_HID);
    agg1_kernel<<<N_NODES, 256, 0, stream>>>(rowoff, csrsrc, as1, ad1, h1b, bg1, x2h, x2l);

    // --- GAT layer 2: transform + fused alpha ---
    gemm_mfma_kernel<N_OUT, 2><<<(N_NODES + 63) / 64, 256, 0, stream>>>(
        x2h, x2l, wtg2h, wtg2l, nullptr, asrc2, adst2,
        h2b, nullptr, as2, ad2, N_NODES, 2 * N_HID);
    agg2_kernel<<<(N_NODES + 3) / 4, 256, 0, stream>>>(rowoff, csrsrc, as2, ad2, h2b, bg2, out);
}

// Round 5
// 667.089 us; speedup vs baseline: 1.0805x; 1.0805x over previous
//
#include <hip/hip_runtime.h>
#include <hip/hip_bf16.h>

#define N_PAPER 30000
#define N_AUTHOR 20000
#define N_NODES 50000
#define N_EDGES 800000
#define D_PAPER 512
#define D_AUTHOR 256
#define N_HID 128
#define N_OUT 64
#define HEADS 2
#define NEG_SLOPE 0.2f

typedef short s16x8 __attribute__((ext_vector_type(8)));
typedef float f32x4 __attribute__((ext_vector_type(4)));
typedef unsigned short ushort_t;

__device__ __forceinline__ unsigned short f2b(float x) {
    unsigned u = __float_as_uint(x);
    u += 0x7fffu + ((u >> 16) & 1u);   // RNE
    return (unsigned short)(u >> 16);
}
__device__ __forceinline__ float b2f(unsigned short h) {
    return __uint_as_float(((unsigned)h) << 16);
}
__device__ __forceinline__ float lrelu(float x) {
    return (x > 0.f) ? x : NEG_SLOPE * x;
}

// ---------------- fused W pre-split+transpose for all 4 weight matrices ----------------
__device__ __forceinline__ void wsplit1(const float* __restrict__ W, ushort_t* __restrict__ WTh,
                                        ushort_t* __restrict__ WTl, int K, int NOUT, int idx) {
    int k = idx / NOUT, c = idx % NOUT;
    float x = W[idx];
    unsigned short h = f2b(x);
    float r = x - b2f(h);
    WTh[c * K + k] = h;
    WTl[c * K + k] = f2b(r);
}

__global__ __launch_bounds__(256) void wsplit_all(
        const float* __restrict__ W1p, const float* __restrict__ W1a,
        const float* __restrict__ Wg1, const float* __restrict__ Wg2,
        ushort_t* wt1ph, ushort_t* wt1pl, ushort_t* wt1ah, ushort_t* wt1al,
        ushort_t* wtg1h, ushort_t* wtg1l, ushort_t* wtg2h, ushort_t* wtg2l) {
    int i = blockIdx.x * 256 + threadIdx.x;
    if (i < 65536)       wsplit1(W1p, wt1ph, wt1pl, D_PAPER, N_HID, i);
    else if (i < 98304)  wsplit1(W1a, wt1ah, wt1al, D_AUTHOR, N_HID, i - 65536);
    else if (i < 131072) wsplit1(Wg1, wtg1h, wtg1l, N_HID, 2 * N_HID, i - 98304);
    else if (i < 147456) wsplit1(Wg2, wtg2h, wtg2l, 2 * N_HID, N_OUT, i - 131072);
}

// ---------------- split-bf16 MFMA GEMM, row-fragment blocked ----------------
// Wave computes RW*16 rows x NF*16 cols. Block = 4 waves = RW*64 rows.
// blockIdx.y = column block (NF*16 cols each); for MODE 1 it is also the head index.
// MODE 0: A fp32; out split bf16 + bias + relu     (encoders)
// MODE 1: A split bf16; out bf16; fused alpha, head = blockIdx.y   (GAT1)
// MODE 2: A split bf16; out bf16; fused alpha, 1 head              (GAT2)
template<int NF, int RW, int MODE>
__global__ __launch_bounds__(256, 1) void gemm_mfma_kernel(
        const void* __restrict__ Av, const ushort_t* __restrict__ Al,
        const ushort_t* __restrict__ WTh, const ushort_t* __restrict__ WTl,
        const float* __restrict__ bias,
        const float* __restrict__ asrc, const float* __restrict__ adst,
        ushort_t* __restrict__ outH, ushort_t* __restrict__ outL,
        float* __restrict__ as_o, float* __restrict__ ad_o,
        int M, int K, int NT) {
    const int tid = threadIdx.x;
    const int wid = tid >> 6, lane = tid & 63;
    const int l16 = lane & 15, kg = lane >> 4;
    const int col0 = blockIdx.y * NF * 16;
    const int wrow0 = blockIdx.x * (RW * 64) + wid * (RW * 16);

    // A row pointers per row-fragment (clamped; OOB rows guarded at store)
    const ushort_t* aph[RW];
    const ushort_t* apl[RW];
    const float* apf[RW];
#pragma unroll
    for (int r = 0; r < RW; r++) {
        int ar = wrow0 + r * 16 + l16;
        ar = (ar < M) ? ar : (M - 1);
        if (MODE == 0) {
            apf[r] = (const float*)Av + (size_t)ar * K + kg * 8;
        } else {
            aph[r] = (const ushort_t*)Av + (size_t)ar * K + kg * 8;
            apl[r] = Al + (size_t)ar * K + kg * 8;
        }
    }
    const ushort_t* wph = WTh + (size_t)(col0 + l16) * K + kg * 8;
    const ushort_t* wpl = WTl + (size_t)(col0 + l16) * K + kg * 8;

    f32x4 acc[RW][NF];
#pragma unroll
    for (int r = 0; r < RW; r++)
#pragma unroll
        for (int f = 0; f < NF; f++)
#pragma unroll
            for (int e = 0; e < 4; e++) acc[r][f][e] = 0.f;

    for (int k0 = 0; k0 < K; k0 += 32) {
        s16x8 ah[RW], al[RW];
#pragma unroll
        for (int r = 0; r < RW; r++) {
            if (MODE == 0) {
                float4 u0 = *reinterpret_cast<const float4*>(apf[r] + k0);
                float4 u1 = *reinterpret_cast<const float4*>(apf[r] + k0 + 4);
                float av[8] = {u0.x, u0.y, u0.z, u0.w, u1.x, u1.y, u1.z, u1.w};
#pragma unroll
                for (int i = 0; i < 8; i++) {
                    unsigned short h = f2b(av[i]);
                    ah[r][i] = (short)h;
                    al[r][i] = (short)f2b(av[i] - b2f(h));
                }
            } else {
                ah[r] = *reinterpret_cast<const s16x8*>(aph[r] + k0);
                al[r] = *reinterpret_cast<const s16x8*>(apl[r] + k0);
            }
        }
#pragma unroll
        for (int f = 0; f < NF; f++) {
            const size_t wo = (size_t)f * 16 * K + k0;
            s16x8 bh = *reinterpret_cast<const s16x8*>(wph + wo);
            s16x8 bl = *reinterpret_cast<const s16x8*>(wpl + wo);
#pragma unroll
            for (int r = 0; r < RW; r++) {
                acc[r][f] = __builtin_amdgcn_mfma_f32_16x16x32_bf16(al[r], bh, acc[r][f], 0, 0, 0);
                acc[r][f] = __builtin_amdgcn_mfma_f32_16x16x32_bf16(ah[r], bl, acc[r][f], 0, 0, 0);
                acc[r][f] = __builtin_amdgcn_mfma_f32_16x16x32_bf16(ah[r], bh, acc[r][f], 0, 0, 0);
            }
        }
    }

    // ---- store ----
#pragma unroll
    for (int r = 0; r < RW; r++) {
        const int orow0 = wrow0 + r * 16 + kg * 4;
#pragma unroll
        for (int f = 0; f < NF; f++) {
            const int col = col0 + f * 16 + l16;
            const float bv = (MODE == 0) ? bias[col] : 0.f;
#pragma unroll
            for (int q = 0; q < 4; q++) {
                const int gr = orow0 + q;
                if (gr >= M) continue;
                float v = acc[r][f][q] + bv;
                if (MODE == 0) {
                    v = fmaxf(v, 0.f);
                    unsigned short h = f2b(v);
                    outH[(size_t)gr * NT + col] = h;
                    outL[(size_t)gr * NT + col] = f2b(v - b2f(h));
                } else {
                    outH[(size_t)gr * NT + col] = f2b(v);
                }
            }
        }
    }

    // ---- fused alpha ----
    if (MODE == 1 || MODE == 2) {
        const int aoff = (MODE == 1) ? blockIdx.y * 128 : 0;
        float avs[NF], avd[NF];
#pragma unroll
        for (int f = 0; f < NF; f++) {
            avs[f] = asrc[aoff + f * 16 + l16];
            avd[f] = adst[aoff + f * 16 + l16];
        }
#pragma unroll
        for (int r = 0; r < RW; r++) {
            float sA[4] = {0.f, 0.f, 0.f, 0.f};
            float dA[4] = {0.f, 0.f, 0.f, 0.f};
#pragma unroll
            for (int f = 0; f < NF; f++)
#pragma unroll
                for (int q = 0; q < 4; q++) {
                    sA[q] += acc[r][f][q] * avs[f];
                    dA[q] += acc[r][f][q] * avd[f];
                }
#pragma unroll
            for (int m = 1; m < 16; m <<= 1)
#pragma unroll
                for (int q = 0; q < 4; q++) {
                    sA[q] += __shfl_xor(sA[q], m);
                    dA[q] += __shfl_xor(dA[q], m);
                }
            if (l16 == 0) {
                const int orow0 = wrow0 + r * 16 + kg * 4;
#pragma unroll
                for (int q = 0; q < 4; q++) {
                    const int row = orow0 + q;
                    if (row < M) {
                        if (MODE == 1) {
                            as_o[row * 2 + blockIdx.y] = sA[q];
                            ad_o[row * 2 + blockIdx.y] = dA[q];
                        } else {
                            as_o[row] = sA[q];
                            ad_o[row] = dA[q];
                        }
                    }
                }
            }
        }
    }
}

// ---------------- CSR build ----------------
__global__ void deg_kernel(const int* __restrict__ dst, int* __restrict__ deg) {
    int e = blockIdx.x * blockDim.x + threadIdx.x;
    if (e < N_EDGES) atomicAdd(&deg[dst[e]], 1);
}

__global__ __launch_bounds__(1024) void scan_kernel(const int* __restrict__ deg,
                                                    int* __restrict__ rowoff,
                                                    int* __restrict__ cursor) {
    __shared__ int tmp[1024];
    const int tid = threadIdx.x;
    constexpr int CH = (N_NODES + 1023) / 1024;
    const int t0 = tid * CH;
    int s = 0;
    for (int i = 0; i < CH; i++) {
        int idx = t0 + i;
        if (idx < N_NODES) s += deg[idx];
    }
    tmp[tid] = s;
    __syncthreads();
    for (int off = 1; off < 1024; off <<= 1) {
        int t = (tid >= off) ? tmp[tid - off] : 0;
        __syncthreads();
        tmp[tid] += t;
        __syncthreads();
    }
    int run = tmp[tid] - s;
    for (int i = 0; i < CH; i++) {
        int idx = t0 + i;
        if (idx < N_NODES) {
            rowoff[idx] = run;
            cursor[idx] = run;
            run += deg[idx];
        }
    }
    if (tid == 1023) rowoff[N_NODES] = tmp[1023];
}

__global__ void scatter_kernel(const int* __restrict__ src, const int* __restrict__ dst,
                               int* __restrict__ cursor, int* __restrict__ csr_src) {
    int e = blockIdx.x * blockDim.x + threadIdx.x;
    if (e >= N_EDGES) return;
    int d = dst[e];
    int pos = atomicAdd(&cursor[d], 1);
    csr_src[pos] = src[e];
}

// ---------------- layer-1 aggregation (R3 structure: thread = channel, unconditional) ----
__global__ __launch_bounds__(256) void agg1_kernel(
        const int* __restrict__ rowoff, const int* __restrict__ csr,
        const float* __restrict__ as_, const float* __restrict__ ad_,
        const ushort_t* __restrict__ hb, const float* __restrict__ bias,
        ushort_t* __restrict__ x2h, ushort_t* __restrict__ x2l) {
    const int n = blockIdx.x;
    const int tid = threadIdx.x;
    const int hd = tid >> 7;
    __shared__ int s_src[256];
    __shared__ float s_w[2][256];
    const float adv0 = ad_[n * 2], adv1 = ad_[n * 2 + 1];
    const int r0 = rowoff[n], r1 = rowoff[n + 1];
    float acc = 0.f, wsum = 0.f;
    for (int base = r0; base < r1; base += 256) {
        const int cnt = min(256, r1 - base);
        __syncthreads();
        if (tid < cnt) {
            int s = csr[base + tid];
            s_src[tid] = s;
            s_w[0][tid] = __expf(lrelu(as_[s * 2 + 0] + adv0));
            s_w[1][tid] = __expf(lrelu(as_[s * 2 + 1] + adv1));
        }
        __syncthreads();
#pragma unroll 4
        for (int j = 0; j < cnt; j++) {
            float w = s_w[hd][j];
            acc += b2f(hb[(size_t)s_src[j] * 256 + tid]) * w;
            wsum += w;
        }
    }
    float o = acc / (wsum + 1e-16f) + bias[tid];
    o = (o > 0.f) ? o : (__expf(o) - 1.f);  // ELU
    unsigned short h = f2b(o);
    x2h[(size_t)n * 256 + tid] = h;
    x2l[(size_t)n * 256 + tid] = f2b(o - b2f(h));
}

// ---------------- layer-2 aggregation: wave per node, bf16 gather ----------------
__global__ __launch_bounds__(256) void agg2_kernel(
        const int* __restrict__ rowoff, const int* __restrict__ csr,
        const float* __restrict__ as_, const float* __restrict__ ad_,
        const ushort_t* __restrict__ h2b, const float* __restrict__ bias,
        float* __restrict__ out) {
    const int wid = threadIdx.x >> 6, lane = threadIdx.x & 63;
    const int n = blockIdx.x * 4 + wid;
    if (n >= N_NODES) return;
    const int c2 = lane & 31;
    const int half = lane >> 5;
    const float adv = ad_[n];
    const int r0 = rowoff[n], r1 = rowoff[n + 1];
    float acc0 = 0.f, acc1 = 0.f, wsum = 0.f;

    for (int base = r0; base < r1; base += 64) {
        const int cnt = min(64, r1 - base);
        int s = 0;
        float w = 0.f;
        if (lane < cnt) {
            s = csr[base + lane];
            w = __expf(lrelu(as_[s] + adv));
        }
        const int half_rounds = (cnt + 1) >> 1;
#pragma unroll 4
        for (int jj = 0; jj < half_rounds; jj++) {
            const int j = jj * 2 + half;
            const int sb = __shfl(s, j);
            const float wb = __shfl(w, j);
            if (j < cnt) {
                const unsigned v = *reinterpret_cast<const unsigned*>(
                    h2b + (size_t)sb * 64 + 2 * c2);
                acc0 += b2f((unsigned short)(v & 0xffffu)) * wb;
                acc1 += b2f((unsigned short)(v >> 16)) * wb;
                wsum += wb;
            }
        }
    }
    acc0 += __shfl_xor(acc0, 32);
    acc1 += __shfl_xor(acc1, 32);
    wsum += __shfl_xor(wsum, 32);
    if (half == 0) {
        const float inv = 1.f / (wsum + 1e-16f);
        float2 o;
        o.x = acc0 * inv + bias[2 * c2];
        o.y = acc1 * inv + bias[2 * c2 + 1];
        *reinterpret_cast<float2*>(out + (size_t)n * 64 + 2 * c2) = o;
    }
}

// ---------------- launch ----------------
extern "C" void kernel_launch(void* const* d_in, const int* in_sizes, int n_in,
                              void* d_out, int out_size, void* d_ws, size_t ws_size,
                              hipStream_t stream) {
    const float* x_paper  = (const float*)d_in[0];
    const float* x_author = (const float*)d_in[1];
    const int*   edge_idx = (const int*)d_in[2];
    const float* W1p = (const float*)d_in[3];
    const float* b1p = (const float*)d_in[4];
    const float* W1a = (const float*)d_in[5];
    const float* b1a = (const float*)d_in[6];
    const float* Wg1 = (const float*)d_in[7];
    const float* asrc1 = (const float*)d_in[8];
    const float* adst1 = (const float*)d_in[9];
    const float* bg1 = (const float*)d_in[10];
    const float* Wg2 = (const float*)d_in[11];
    const float* asrc2 = (const float*)d_in[12];
    const float* adst2 = (const float*)d_in[13];
    const float* bg2 = (const float*)d_in[14];
    float* out = (float*)d_out;

    const int* src = edge_idx;
    const int* dst = edge_idx + N_EDGES;

    char* ws = (char*)d_ws;
    size_t off = 0;
    auto alloc = [&](size_t bytes) -> void* {
        void* p = ws + off;
        off += (bytes + 255) & ~(size_t)255;
        return p;
    };
    ushort_t* xh    = (ushort_t*)alloc((size_t)N_NODES * N_HID * 2);
    ushort_t* xl    = (ushort_t*)alloc((size_t)N_NODES * N_HID * 2);
    ushort_t* h1b   = (ushort_t*)alloc((size_t)N_NODES * 2 * N_HID * 2);
    ushort_t* x2h   = (ushort_t*)alloc((size_t)N_NODES * 2 * N_HID * 2);
    ushort_t* x2l   = (ushort_t*)alloc((size_t)N_NODES * 2 * N_HID * 2);
    ushort_t* h2b   = (ushort_t*)alloc((size_t)N_NODES * N_OUT * 2);
    ushort_t* wt1ph = (ushort_t*)alloc((size_t)D_PAPER * N_HID * 2);
    ushort_t* wt1pl = (ushort_t*)alloc((size_t)D_PAPER * N_HID * 2);
    ushort_t* wt1ah = (ushort_t*)alloc((size_t)D_AUTHOR * N_HID * 2);
    ushort_t* wt1al = (ushort_t*)alloc((size_t)D_AUTHOR * N_HID * 2);
    ushort_t* wtg1h = (ushort_t*)alloc((size_t)N_HID * 2 * N_HID * 2);
    ushort_t* wtg1l = (ushort_t*)alloc((size_t)N_HID * 2 * N_HID * 2);
    ushort_t* wtg2h = (ushort_t*)alloc((size_t)2 * N_HID * N_OUT * 2);
    ushort_t* wtg2l = (ushort_t*)alloc((size_t)2 * N_HID * N_OUT * 2);
    float*    as1   = (float*)alloc((size_t)N_NODES * HEADS * 4);
    float*    ad1   = (float*)alloc((size_t)N_NODES * HEADS * 4);
    float*    as2   = (float*)alloc((size_t)N_NODES * 4);
    float*    ad2   = (float*)alloc((size_t)N_NODES * 4);
    int*      deg    = (int*)alloc((size_t)N_NODES * 4);
    int*      rowoff = (int*)alloc((size_t)(N_NODES + 1) * 4);
    int*      cursor = (int*)alloc((size_t)N_NODES * 4);
    int*      csrsrc = (int*)alloc((size_t)N_EDGES * 4);

    const int EB = (N_EDGES + 255) / 256;

    // --- W pre-split/transpose ---
    wsplit_all<<<576, 256, 0, stream>>>(W1p, W1a, Wg1, Wg2,
        wt1ph, wt1pl, wt1ah, wt1al, wtg1h, wtg1l, wtg2h, wtg2l);

    // --- CSR build ---
    hipMemsetAsync(deg, 0, N_NODES * 4, stream);
    deg_kernel<<<EB, 256, 0, stream>>>(dst, deg);
    scan_kernel<<<1, 1024, 0, stream>>>(deg, rowoff, cursor);
    scatter_kernel<<<EB, 256, 0, stream>>>(src, dst, cursor, csrsrc);

    // --- encoders: fp32 in, split-bf16 out (NF=8, RW=4: 256 rows/block) ---
    gemm_mfma_kernel<8, 4, 0><<<dim3((N_PAPER + 255) / 256, 1), 256, 0, stream>>>(
        x_paper, nullptr, wt1ph, wt1pl, b1p, nullptr, nullptr,
        xh, xl, nullptr, nullptr, N_PAPER, D_PAPER, N_HID);
    gemm_mfma_kernel<8, 4, 0><<<dim3((N_AUTHOR + 255) / 256, 1), 256, 0, stream>>>(
        x_author, nullptr, wt1ah, wt1al, b1a, nullptr, nullptr,
        xh + (size_t)N_PAPER * N_HID, xl + (size_t)N_PAPER * N_HID,
        nullptr, nullptr, N_AUTHOR, D_AUTHOR, N_HID);

    // --- GAT layer 1: transform + fused alpha (col-block = head) ---
    gemm_mfma_kernel<8, 4, 1><<<dim3((N_NODES + 255) / 256, 2), 256, 0, stream>>>(
        xh, xl, wtg1h, wtg1l, nullptr, asrc1, adst1,
        h1b, nullptr, as1, ad1, N_NODES, N_HID, 2 * N_HID);
    agg1_kernel<<<N_NODES, 256, 0, stream>>>(rowoff, csrsrc, as1, ad1, h1b, bg1, x2h, x2l);

    // --- GAT layer 2: transform + fused alpha ---
    gemm_mfma_kernel<4, 4, 2><<<dim3((N_NODES + 255) / 256, 1), 256, 0, stream>>>(
        x2h, x2l, wtg2h, wtg2l, nullptr, asrc2, adst2,
        h2b, nullptr, as2, ad2, N_NODES, 2 * N_HID, N_OUT);
    agg2_kernel<<<(N_NODES + 3) / 4, 256, 0, stream>>>(rowoff, csrsrc, as2, ad2, h2b, bg2, out);
}

// Round 7
// 520.146 us; speedup vs baseline: 1.3857x; 1.2825x over previous
//
#include <hip/hip_runtime.h>
#include <hip/hip_bf16.h>

#define N_PAPER 30000
#define N_AUTHOR 20000
#define N_NODES 50000
#define N_EDGES 800000
#define D_PAPER 512
#define D_AUTHOR 256
#define N_HID 128
#define N_OUT 64
#define HEADS 2
#define NEG_SLOPE 0.2f

#define SCAN_B 1024
#define SCAN_NB ((N_NODES + SCAN_B - 1) / SCAN_B)   // 49

typedef short s16x8 __attribute__((ext_vector_type(8)));
typedef float f32x4 __attribute__((ext_vector_type(4)));
typedef unsigned short ushort_t;

__device__ __forceinline__ unsigned short f2b(float x) {
    unsigned u = __float_as_uint(x);
    u += 0x7fffu + ((u >> 16) & 1u);   // RNE
    return (unsigned short)(u >> 16);
}
__device__ __forceinline__ float b2f(unsigned short h) {
    return __uint_as_float(((unsigned)h) << 16);
}
__device__ __forceinline__ float lrelu(float x) {
    return (x > 0.f) ? x : NEG_SLOPE * x;
}

// ---------------- fused W pre-split+transpose for all 4 weight matrices ----------------
__device__ __forceinline__ void wsplit1(const float* __restrict__ W, ushort_t* __restrict__ WTh,
                                        ushort_t* __restrict__ WTl, int K, int NOUT, int idx) {
    int k = idx / NOUT, c = idx % NOUT;
    float x = W[idx];
    unsigned short h = f2b(x);
    float r = x - b2f(h);
    WTh[c * K + k] = h;
    WTl[c * K + k] = f2b(r);
}

__global__ __launch_bounds__(256) void wsplit_all(
        const float* __restrict__ W1p, const float* __restrict__ W1a,
        const float* __restrict__ Wg1, const float* __restrict__ Wg2,
        ushort_t* wt1ph, ushort_t* wt1pl, ushort_t* wt1ah, ushort_t* wt1al,
        ushort_t* wtg1h, ushort_t* wtg1l, ushort_t* wtg2h, ushort_t* wtg2l) {
    int i = blockIdx.x * 256 + threadIdx.x;
    if (i < 65536)       wsplit1(W1p, wt1ph, wt1pl, D_PAPER, N_HID, i);
    else if (i < 98304)  wsplit1(W1a, wt1ah, wt1al, D_AUTHOR, N_HID, i - 65536);
    else if (i < 131072) wsplit1(Wg1, wtg1h, wtg1l, N_HID, 2 * N_HID, i - 98304);
    else if (i < 147456) wsplit1(Wg2, wtg2h, wtg2l, 2 * N_HID, N_OUT, i - 131072);
}

// ---------------- split-bf16 MFMA GEMM, row-fragment blocked ----------------
template<int NF, int RW, int MODE>
__global__ __launch_bounds__(256, 1) void gemm_mfma_kernel(
        const void* __restrict__ Av, const ushort_t* __restrict__ Al,
        const ushort_t* __restrict__ WTh, const ushort_t* __restrict__ WTl,
        const float* __restrict__ bias,
        const float* __restrict__ asrc, const float* __restrict__ adst,
        ushort_t* __restrict__ outH, ushort_t* __restrict__ outL,
        float* __restrict__ as_o, float* __restrict__ ad_o,
        int M, int K, int NT) {
    const int tid = threadIdx.x;
    const int wid = tid >> 6, lane = tid & 63;
    const int l16 = lane & 15, kg = lane >> 4;
    const int col0 = blockIdx.y * NF * 16;
    const int wrow0 = blockIdx.x * (RW * 64) + wid * (RW * 16);

    const ushort_t* aph[RW];
    const ushort_t* apl[RW];
    const float* apf[RW];
#pragma unroll
    for (int r = 0; r < RW; r++) {
        int ar = wrow0 + r * 16 + l16;
        ar = (ar < M) ? ar : (M - 1);
        if (MODE == 0) {
            apf[r] = (const float*)Av + (size_t)ar * K + kg * 8;
        } else {
            aph[r] = (const ushort_t*)Av + (size_t)ar * K + kg * 8;
            apl[r] = Al + (size_t)ar * K + kg * 8;
        }
    }
    const ushort_t* wph = WTh + (size_t)(col0 + l16) * K + kg * 8;
    const ushort_t* wpl = WTl + (size_t)(col0 + l16) * K + kg * 8;

    f32x4 acc[RW][NF];
#pragma unroll
    for (int r = 0; r < RW; r++)
#pragma unroll
        for (int f = 0; f < NF; f++)
#pragma unroll
            for (int e = 0; e < 4; e++) acc[r][f][e] = 0.f;

    for (int k0 = 0; k0 < K; k0 += 32) {
        s16x8 ah[RW], al[RW];
#pragma unroll
        for (int r = 0; r < RW; r++) {
            if (MODE == 0) {
                float4 u0 = *reinterpret_cast<const float4*>(apf[r] + k0);
                float4 u1 = *reinterpret_cast<const float4*>(apf[r] + k0 + 4);
                float av[8] = {u0.x, u0.y, u0.z, u0.w, u1.x, u1.y, u1.z, u1.w};
#pragma unroll
                for (int i = 0; i < 8; i++) {
                    unsigned short h = f2b(av[i]);
                    ah[r][i] = (short)h;
                    al[r][i] = (short)f2b(av[i] - b2f(h));
                }
            } else {
                ah[r] = *reinterpret_cast<const s16x8*>(aph[r] + k0);
                al[r] = *reinterpret_cast<const s16x8*>(apl[r] + k0);
            }
        }
#pragma unroll
        for (int f = 0; f < NF; f++) {
            const size_t wo = (size_t)f * 16 * K + k0;
            s16x8 bh = *reinterpret_cast<const s16x8*>(wph + wo);
            s16x8 bl = *reinterpret_cast<const s16x8*>(wpl + wo);
#pragma unroll
            for (int r = 0; r < RW; r++) {
                acc[r][f] = __builtin_amdgcn_mfma_f32_16x16x32_bf16(al[r], bh, acc[r][f], 0, 0, 0);
                acc[r][f] = __builtin_amdgcn_mfma_f32_16x16x32_bf16(ah[r], bl, acc[r][f], 0, 0, 0);
                acc[r][f] = __builtin_amdgcn_mfma_f32_16x16x32_bf16(ah[r], bh, acc[r][f], 0, 0, 0);
            }
        }
    }

#pragma unroll
    for (int r = 0; r < RW; r++) {
        const int orow0 = wrow0 + r * 16 + kg * 4;
#pragma unroll
        for (int f = 0; f < NF; f++) {
            const int col = col0 + f * 16 + l16;
            const float bv = (MODE == 0) ? bias[col] : 0.f;
#pragma unroll
            for (int q = 0; q < 4; q++) {
                const int gr = orow0 + q;
                if (gr >= M) continue;
                float v = acc[r][f][q] + bv;
                if (MODE == 0) {
                    v = fmaxf(v, 0.f);
                    unsigned short h = f2b(v);
                    outH[(size_t)gr * NT + col] = h;
                    outL[(size_t)gr * NT + col] = f2b(v - b2f(h));
                } else {
                    outH[(size_t)gr * NT + col] = f2b(v);
                }
            }
        }
    }

    if (MODE == 1 || MODE == 2) {
        const int aoff = (MODE == 1) ? blockIdx.y * 128 : 0;
        float avs[NF], avd[NF];
#pragma unroll
        for (int f = 0; f < NF; f++) {
            avs[f] = asrc[aoff + f * 16 + l16];
            avd[f] = adst[aoff + f * 16 + l16];
        }
#pragma unroll
        for (int r = 0; r < RW; r++) {
            float sA[4] = {0.f, 0.f, 0.f, 0.f};
            float dA[4] = {0.f, 0.f, 0.f, 0.f};
#pragma unroll
            for (int f = 0; f < NF; f++)
#pragma unroll
                for (int q = 0; q < 4; q++) {
                    sA[q] += acc[r][f][q] * avs[f];
                    dA[q] += acc[r][f][q] * avd[f];
                }
#pragma unroll
            for (int m = 1; m < 16; m <<= 1)
#pragma unroll
                for (int q = 0; q < 4; q++) {
                    sA[q] += __shfl_xor(sA[q], m);
                    dA[q] += __shfl_xor(dA[q], m);
                }
            if (l16 == 0) {
                const int orow0 = wrow0 + r * 16 + kg * 4;
#pragma unroll
                for (int q = 0; q < 4; q++) {
                    const int row = orow0 + q;
                    if (row < M) {
                        if (MODE == 1) {
                            as_o[row * 2 + blockIdx.y] = sA[q];
                            ad_o[row * 2 + blockIdx.y] = dA[q];
                        } else {
                            as_o[row] = sA[q];
                            ad_o[row] = dA[q];
                        }
                    }
                }
            }
        }
    }
}

// ---------------- CSR build ----------------
__global__ void deg_kernel(const int* __restrict__ dst, int* __restrict__ deg) {
    int e = blockIdx.x * blockDim.x + threadIdx.x;
    if (e < N_EDGES) atomicAdd(&deg[dst[e]], 1);
}

// Phase A: per-block inclusive scan + block totals
__global__ __launch_bounds__(SCAN_B) void scanA_kernel(const int* __restrict__ deg,
                                                       int* __restrict__ incl,
                                                       int* __restrict__ partials) {
    __shared__ int tmp[SCAN_B];
    const int tid = threadIdx.x;
    const int i = blockIdx.x * SCAN_B + tid;
    int v = (i < N_NODES) ? deg[i] : 0;
    tmp[tid] = v;
    __syncthreads();
    for (int off = 1; off < SCAN_B; off <<= 1) {
        int t = (tid >= off) ? tmp[tid - off] : 0;
        __syncthreads();
        tmp[tid] += t;
        __syncthreads();
    }
    if (i < N_NODES) incl[i] = tmp[tid];
    if (tid == SCAN_B - 1) partials[blockIdx.x] = tmp[tid];
}

// Phase B: exclusive scan of block totals (tiny)
__global__ __launch_bounds__(64) void scanB_kernel(int* __restrict__ partials,
                                                   int* __restrict__ poff) {
    if (threadIdx.x == 0) {
        int run = 0;
        for (int b = 0; b < SCAN_NB; b++) {
            poff[b] = run;
            run += partials[b];
        }
        poff[SCAN_NB] = run;
    }
}

// Phase C: apply offsets -> rowoff (exclusive), cursor
__global__ __launch_bounds__(SCAN_B) void scanC_kernel(const int* __restrict__ deg,
                                                       const int* __restrict__ incl,
                                                       const int* __restrict__ poff,
                                                       int* __restrict__ rowoff,
                                                       int* __restrict__ cursor) {
    const int i = blockIdx.x * SCAN_B + threadIdx.x;
    if (i >= N_NODES) return;
    const int excl = poff[blockIdx.x] + incl[i] - deg[i];
    rowoff[i] = excl;
    cursor[i] = excl;
    if (i == N_NODES - 1) rowoff[N_NODES] = poff[blockIdx.x] + incl[i];
}

__global__ void scatter_kernel(const int* __restrict__ src, const int* __restrict__ dst,
                               int* __restrict__ cursor, int* __restrict__ csr_src) {
    int e = blockIdx.x * blockDim.x + threadIdx.x;
    if (e >= N_EDGES) return;
    int d = dst[e];
    int pos = atomicAdd(&cursor[d], 1);
    csr_src[pos] = src[e];
}

// ---------------- layer-1 aggregation: 128 threads, thread = channel pair ----------------
__global__ __launch_bounds__(128) void agg1_kernel(
        const int* __restrict__ rowoff, const int* __restrict__ csr,
        const float* __restrict__ as_, const float* __restrict__ ad_,
        const ushort_t* __restrict__ hb, const float* __restrict__ bias,
        ushort_t* __restrict__ x2h, ushort_t* __restrict__ x2l) {
    const int n = blockIdx.x;
    const int tid = threadIdx.x;          // channel pair (2*tid, 2*tid+1)
    const int head = tid >> 6;
    __shared__ int s_src[128];
    __shared__ float s_w[2][128];
    const float adv0 = ad_[n * 2], adv1 = ad_[n * 2 + 1];
    const int r0 = rowoff[n], r1 = rowoff[n + 1];
    float acc0 = 0.f, acc1 = 0.f, wsum = 0.f;
    for (int base = r0; base < r1; base += 128) {
        const int cnt = min(128, r1 - base);
        __syncthreads();
        if (tid < cnt) {
            int s = csr[base + tid];
            s_src[tid] = s;
            const float2 a2 = *reinterpret_cast<const float2*>(as_ + s * 2);
            s_w[0][tid] = __expf(lrelu(a2.x + adv0));
            s_w[1][tid] = __expf(lrelu(a2.y + adv1));
        }
        __syncthreads();
#pragma unroll 4
        for (int j = 0; j < cnt; j++) {
            const float w = s_w[head][j];
            const unsigned v = *reinterpret_cast<const unsigned*>(
                hb + (size_t)s_src[j] * 256 + 2 * tid);
            acc0 += b2f((unsigned short)(v & 0xffffu)) * w;
            acc1 += b2f((unsigned short)(v >> 16)) * w;
            wsum += w;
        }
    }
    const float inv = 1.f / (wsum + 1e-16f);
    const float2 bv = *reinterpret_cast<const float2*>(bias + 2 * tid);
    float o0 = acc0 * inv + bv.x;
    float o1 = acc1 * inv + bv.y;
    o0 = (o0 > 0.f) ? o0 : (__expf(o0) - 1.f);
    o1 = (o1 > 0.f) ? o1 : (__expf(o1) - 1.f);
    ushort2 hh, ll;
    hh.x = f2b(o0); ll.x = f2b(o0 - b2f(hh.x));
    hh.y = f2b(o1); ll.y = f2b(o1 - b2f(hh.y));
    *reinterpret_cast<ushort2*>(x2h + (size_t)n * 256 + 2 * tid) = hh;
    *reinterpret_cast<ushort2*>(x2l + (size_t)n * 256 + 2 * tid) = ll;
}

// ---------------- layer-2 aggregation: wave per node, bf16 gather ----------------
__global__ __launch_bounds__(256) void agg2_kernel(
        const int* __restrict__ rowoff, const int* __restrict__ csr,
        const float* __restrict__ as_, const float* __restrict__ ad_,
        const ushort_t* __restrict__ h2b, const float* __restrict__ bias,
        float* __restrict__ out) {
    const int wid = threadIdx.x >> 6, lane = threadIdx.x & 63;
    const int n = blockIdx.x * 4 + wid;
    if (n >= N_NODES) return;
    const int c2 = lane & 31;
    const int half = lane >> 5;
    const float adv = ad_[n];
    const int r0 = rowoff[n], r1 = rowoff[n + 1];
    float acc0 = 0.f, acc1 = 0.f, wsum = 0.f;

    for (int base = r0; base < r1; base += 64) {
        const int cnt = min(64, r1 - base);
        int s = 0;
        float w = 0.f;
        if (lane < cnt) {
            s = csr[base + lane];
            w = __expf(lrelu(as_[s] + adv));
        }
        const int half_rounds = (cnt + 1) >> 1;
#pragma unroll 4
        for (int jj = 0; jj < half_rounds; jj++) {
            const int j = jj * 2 + half;
            const int sb = __shfl(s, j);
            const float wb = __shfl(w, j);
            if (j < cnt) {
                const unsigned v = *reinterpret_cast<const unsigned*>(
                    h2b + (size_t)sb * 64 + 2 * c2);
                acc0 += b2f((unsigned short)(v & 0xffffu)) * wb;
                acc1 += b2f((unsigned short)(v >> 16)) * wb;
                wsum += wb;
            }
        }
    }
    acc0 += __shfl_xor(acc0, 32);
    acc1 += __shfl_xor(acc1, 32);
    wsum += __shfl_xor(wsum, 32);
    if (half == 0) {
        const float inv = 1.f / (wsum + 1e-16f);
        float2 o;
        o.x = acc0 * inv + bias[2 * c2];
        o.y = acc1 * inv + bias[2 * c2 + 1];
        *reinterpret_cast<float2*>(out + (size_t)n * 64 + 2 * c2) = o;
    }
}

// ---------------- launch ----------------
extern "C" void kernel_launch(void* const* d_in, const int* in_sizes, int n_in,
                              void* d_out, int out_size, void* d_ws, size_t ws_size,
                              hipStream_t stream) {
    const float* x_paper  = (const float*)d_in[0];
    const float* x_author = (const float*)d_in[1];
    const int*   edge_idx = (const int*)d_in[2];
    const float* W1p = (const float*)d_in[3];
    const float* b1p = (const float*)d_in[4];
    const float* W1a = (const float*)d_in[5];
    const float* b1a = (const float*)d_in[6];
    const float* Wg1 = (const float*)d_in[7];
    const float* asrc1 = (const float*)d_in[8];
    const float* adst1 = (const float*)d_in[9];
    const float* bg1 = (const float*)d_in[10];
    const float* Wg2 = (const float*)d_in[11];
    const float* asrc2 = (const float*)d_in[12];
    const float* adst2 = (const float*)d_in[13];
    const float* bg2 = (const float*)d_in[14];
    float* out = (float*)d_out;

    const int* src = edge_idx;
    const int* dst = edge_idx + N_EDGES;

    char* ws = (char*)d_ws;
    size_t off = 0;
    auto alloc = [&](size_t bytes) -> void* {
        void* p = ws + off;
        off += (bytes + 255) & ~(size_t)255;
        return p;
    };
    ushort_t* xh    = (ushort_t*)alloc((size_t)N_NODES * N_HID * 2);
    ushort_t* xl    = (ushort_t*)alloc((size_t)N_NODES * N_HID * 2);
    ushort_t* h1b   = (ushort_t*)alloc((size_t)N_NODES * 2 * N_HID * 2);
    ushort_t* x2h   = (ushort_t*)alloc((size_t)N_NODES * 2 * N_HID * 2);
    ushort_t* x2l   = (ushort_t*)alloc((size_t)N_NODES * 2 * N_HID * 2);
    ushort_t* h2b   = (ushort_t*)alloc((size_t)N_NODES * N_OUT * 2);
    ushort_t* wt1ph = (ushort_t*)alloc((size_t)D_PAPER * N_HID * 2);
    ushort_t* wt1pl = (ushort_t*)alloc((size_t)D_PAPER * N_HID * 2);
    ushort_t* wt1ah = (ushort_t*)alloc((size_t)D_AUTHOR * N_HID * 2);
    ushort_t* wt1al = (ushort_t*)alloc((size_t)D_AUTHOR * N_HID * 2);
    ushort_t* wtg1h = (ushort_t*)alloc((size_t)N_HID * 2 * N_HID * 2);
    ushort_t* wtg1l = (ushort_t*)alloc((size_t)N_HID * 2 * N_HID * 2);
    ushort_t* wtg2h = (ushort_t*)alloc((size_t)2 * N_HID * N_OUT * 2);
    ushort_t* wtg2l = (ushort_t*)alloc((size_t)2 * N_HID * N_OUT * 2);
    float*    as1   = (float*)alloc((size_t)N_NODES * HEADS * 4);
    float*    ad1   = (float*)alloc((size_t)N_NODES * HEADS * 4);
    float*    as2   = (float*)alloc((size_t)N_NODES * 4);
    float*    ad2   = (float*)alloc((size_t)N_NODES * 4);
    int*      deg    = (int*)alloc((size_t)N_NODES * 4);
    int*      incl   = (int*)alloc((size_t)N_NODES * 4);
    int*      parts  = (int*)alloc((size_t)(SCAN_NB + 1) * 4);
    int*      poff   = (int*)alloc((size_t)(SCAN_NB + 1) * 4);
    int*      rowoff = (int*)alloc((size_t)(N_NODES + 1) * 4);
    int*      cursor = (int*)alloc((size_t)N_NODES * 4);
    int*      csrsrc = (int*)alloc((size_t)N_EDGES * 4);

    const int EB = (N_EDGES + 255) / 256;

    // --- W pre-split/transpose ---
    wsplit_all<<<576, 256, 0, stream>>>(W1p, W1a, Wg1, Wg2,
        wt1ph, wt1pl, wt1ah, wt1al, wtg1h, wtg1l, wtg2h, wtg2l);

    // --- CSR build (multi-block scan) ---
    hipMemsetAsync(deg, 0, N_NODES * 4, stream);
    deg_kernel<<<EB, 256, 0, stream>>>(dst, deg);
    scanA_kernel<<<SCAN_NB, SCAN_B, 0, stream>>>(deg, incl, parts);
    scanB_kernel<<<1, 64, 0, stream>>>(parts, poff);
    scanC_kernel<<<SCAN_NB, SCAN_B, 0, stream>>>(deg, incl, poff, rowoff, cursor);
    scatter_kernel<<<EB, 256, 0, stream>>>(src, dst, cursor, csrsrc);

    // --- encoders: fp32 in, split-bf16 out ---
    gemm_mfma_kernel<8, 4, 0><<<dim3((N_PAPER + 255) / 256, 1), 256, 0, stream>>>(
        x_paper, nullptr, wt1ph, wt1pl, b1p, nullptr, nullptr,
        xh, xl, nullptr, nullptr, N_PAPER, D_PAPER, N_HID);
    gemm_mfma_kernel<8, 4, 0><<<dim3((N_AUTHOR + 255) / 256, 1), 256, 0, stream>>>(
        x_author, nullptr, wt1ah, wt1al, b1a, nullptr, nullptr,
        xh + (size_t)N_PAPER * N_HID, xl + (size_t)N_PAPER * N_HID,
        nullptr, nullptr, N_AUTHOR, D_AUTHOR, N_HID);

    // --- GAT layer 1: transform + fused alpha ---
    gemm_mfma_kernel<8, 4, 1><<<dim3((N_NODES + 255) / 256, 2), 256, 0, stream>>>(
        xh, xl, wtg1h, wtg1l, nullptr, asrc1, adst1,
        h1b, nullptr, as1, ad1, N_NODES, N_HID, 2 * N_HID);
    agg1_kernel<<<N_NODES, 128, 0, stream>>>(rowoff, csrsrc, as1, ad1, h1b, bg1, x2h, x2l);

    // --- GAT layer 2: transform + fused alpha ---
    gemm_mfma_kernel<4, 4, 2><<<dim3((N_NODES + 255) / 256, 1), 256, 0, stream>>>(
        x2h, x2l, wtg2h, wtg2l, nullptr, asrc2, adst2,
        h2b, nullptr, as2, ad2, N_NODES, 2 * N_HID, N_OUT);
    agg2_kernel<<<(N_NODES + 3) / 4, 256, 0, stream>>>(rowoff, csrsrc, as2, ad2, h2b, bg2, out);
}

// Round 8
// 508.883 us; speedup vs baseline: 1.4164x; 1.0221x over previous
//
#include <hip/hip_runtime.h>
#include <hip/hip_bf16.h>

#define N_PAPER 30000
#define N_AUTHOR 20000
#define N_NODES 50000
#define N_EDGES 800000
#define D_PAPER 512
#define D_AUTHOR 256
#define N_HID 128
#define N_OUT 64
#define HEADS 2
#define NEG_SLOPE 0.2f

#define SCAN_B 1024
#define SCAN_NB ((N_NODES + SCAN_B - 1) / SCAN_B)   // 49

typedef short s16x8 __attribute__((ext_vector_type(8)));
typedef float f32x4 __attribute__((ext_vector_type(4)));
typedef unsigned short ushort_t;

__device__ __forceinline__ unsigned short f2b(float x) {
    unsigned u = __float_as_uint(x);
    u += 0x7fffu + ((u >> 16) & 1u);   // RNE
    return (unsigned short)(u >> 16);
}
__device__ __forceinline__ float b2f(unsigned short h) {
    return __uint_as_float(((unsigned)h) << 16);
}
__device__ __forceinline__ float lrelu(float x) {
    return (x > 0.f) ? x : NEG_SLOPE * x;
}

// ---------------- fused W pre-split+transpose for all 4 weight matrices ----------------
__device__ __forceinline__ void wsplit1(const float* __restrict__ W, ushort_t* __restrict__ WTh,
                                        ushort_t* __restrict__ WTl, int K, int NOUT, int idx) {
    int k = idx / NOUT, c = idx % NOUT;
    float x = W[idx];
    unsigned short h = f2b(x);
    float r = x - b2f(h);
    WTh[c * K + k] = h;
    WTl[c * K + k] = f2b(r);
}

__global__ __launch_bounds__(256) void wsplit_all(
        const float* __restrict__ W1p, const float* __restrict__ W1a,
        const float* __restrict__ Wg1, const float* __restrict__ Wg2,
        ushort_t* wt1ph, ushort_t* wt1pl, ushort_t* wt1ah, ushort_t* wt1al,
        ushort_t* wtg1h, ushort_t* wtg1l, ushort_t* wtg2h, ushort_t* wtg2l) {
    int i = blockIdx.x * 256 + threadIdx.x;
    if (i < 65536)       wsplit1(W1p, wt1ph, wt1pl, D_PAPER, N_HID, i);
    else if (i < 98304)  wsplit1(W1a, wt1ah, wt1al, D_AUTHOR, N_HID, i - 65536);
    else if (i < 131072) wsplit1(Wg1, wtg1h, wtg1l, N_HID, 2 * N_HID, i - 98304);
    else if (i < 147456) wsplit1(Wg2, wtg2h, wtg2l, 2 * N_HID, N_OUT, i - 131072);
}

// ---------------- split-bf16 MFMA GEMM, row-fragment blocked ----------------
template<int NF, int RW, int MODE>
__global__ __launch_bounds__(256, 2) void gemm_mfma_kernel(
        const void* __restrict__ Av, const ushort_t* __restrict__ Al,
        const ushort_t* __restrict__ WTh, const ushort_t* __restrict__ WTl,
        const float* __restrict__ bias,
        const float* __restrict__ asrc, const float* __restrict__ adst,
        ushort_t* __restrict__ outH, ushort_t* __restrict__ outL,
        float* __restrict__ as_o, float* __restrict__ ad_o,
        int M, int K, int NT) {
    const int tid = threadIdx.x;
    const int wid = tid >> 6, lane = tid & 63;
    const int l16 = lane & 15, kg = lane >> 4;
    const int col0 = blockIdx.y * NF * 16;
    const int wrow0 = blockIdx.x * (RW * 64) + wid * (RW * 16);

    const ushort_t* aph[RW];
    const ushort_t* apl[RW];
    const float* apf[RW];
#pragma unroll
    for (int r = 0; r < RW; r++) {
        int ar = wrow0 + r * 16 + l16;
        ar = (ar < M) ? ar : (M - 1);
        if (MODE == 0) {
            apf[r] = (const float*)Av + (size_t)ar * K + kg * 8;
        } else {
            aph[r] = (const ushort_t*)Av + (size_t)ar * K + kg * 8;
            apl[r] = Al + (size_t)ar * K + kg * 8;
        }
    }
    const ushort_t* wph = WTh + (size_t)(col0 + l16) * K + kg * 8;
    const ushort_t* wpl = WTl + (size_t)(col0 + l16) * K + kg * 8;

    f32x4 acc[RW][NF];
#pragma unroll
    for (int r = 0; r < RW; r++)
#pragma unroll
        for (int f = 0; f < NF; f++)
#pragma unroll
            for (int e = 0; e < 4; e++) acc[r][f][e] = 0.f;

    for (int k0 = 0; k0 < K; k0 += 32) {
        s16x8 ah[RW], al[RW];
#pragma unroll
        for (int r = 0; r < RW; r++) {
            if (MODE == 0) {
                float4 u0 = *reinterpret_cast<const float4*>(apf[r] + k0);
                float4 u1 = *reinterpret_cast<const float4*>(apf[r] + k0 + 4);
                float av[8] = {u0.x, u0.y, u0.z, u0.w, u1.x, u1.y, u1.z, u1.w};
#pragma unroll
                for (int i = 0; i < 8; i++) {
                    unsigned short h = f2b(av[i]);
                    ah[r][i] = (short)h;
                    al[r][i] = (short)f2b(av[i] - b2f(h));
                }
            } else {
                ah[r] = *reinterpret_cast<const s16x8*>(aph[r] + k0);
                al[r] = *reinterpret_cast<const s16x8*>(apl[r] + k0);
            }
        }
#pragma unroll
        for (int f = 0; f < NF; f++) {
            const size_t wo = (size_t)f * 16 * K + k0;
            s16x8 bh = *reinterpret_cast<const s16x8*>(wph + wo);
            s16x8 bl = *reinterpret_cast<const s16x8*>(wpl + wo);
#pragma unroll
            for (int r = 0; r < RW; r++) {
                acc[r][f] = __builtin_amdgcn_mfma_f32_16x16x32_bf16(al[r], bh, acc[r][f], 0, 0, 0);
                acc[r][f] = __builtin_amdgcn_mfma_f32_16x16x32_bf16(ah[r], bl, acc[r][f], 0, 0, 0);
                acc[r][f] = __builtin_amdgcn_mfma_f32_16x16x32_bf16(ah[r], bh, acc[r][f], 0, 0, 0);
            }
        }
    }

#pragma unroll
    for (int r = 0; r < RW; r++) {
        const int orow0 = wrow0 + r * 16 + kg * 4;
#pragma unroll
        for (int f = 0; f < NF; f++) {
            const int col = col0 + f * 16 + l16;
            const float bv = (MODE == 0) ? bias[col] : 0.f;
#pragma unroll
            for (int q = 0; q < 4; q++) {
                const int gr = orow0 + q;
                if (gr >= M) continue;
                float v = acc[r][f][q] + bv;
                if (MODE == 0) {
                    v = fmaxf(v, 0.f);
                    unsigned short h = f2b(v);
                    outH[(size_t)gr * NT + col] = h;
                    outL[(size_t)gr * NT + col] = f2b(v - b2f(h));
                } else {
                    outH[(size_t)gr * NT + col] = f2b(v);
                }
            }
        }
    }

    if (MODE == 1 || MODE == 2) {
        const int aoff = (MODE == 1) ? blockIdx.y * 128 : 0;
        float avs[NF], avd[NF];
#pragma unroll
        for (int f = 0; f < NF; f++) {
            avs[f] = asrc[aoff + f * 16 + l16];
            avd[f] = adst[aoff + f * 16 + l16];
        }
#pragma unroll
        for (int r = 0; r < RW; r++) {
            float sA[4] = {0.f, 0.f, 0.f, 0.f};
            float dA[4] = {0.f, 0.f, 0.f, 0.f};
#pragma unroll
            for (int f = 0; f < NF; f++)
#pragma unroll
                for (int q = 0; q < 4; q++) {
                    sA[q] += acc[r][f][q] * avs[f];
                    dA[q] += acc[r][f][q] * avd[f];
                }
#pragma unroll
            for (int m = 1; m < 16; m <<= 1)
#pragma unroll
                for (int q = 0; q < 4; q++) {
                    sA[q] += __shfl_xor(sA[q], m);
                    dA[q] += __shfl_xor(dA[q], m);
                }
            if (l16 == 0) {
                const int orow0 = wrow0 + r * 16 + kg * 4;
#pragma unroll
                for (int q = 0; q < 4; q++) {
                    const int row = orow0 + q;
                    if (row < M) {
                        if (MODE == 1) {
                            as_o[row * 2 + blockIdx.y] = sA[q];
                            ad_o[row * 2 + blockIdx.y] = dA[q];
                        } else {
                            as_o[row] = sA[q];
                            ad_o[row] = dA[q];
                        }
                    }
                }
            }
        }
    }
}

// ---------------- CSR build ----------------
__global__ void deg_kernel(const int* __restrict__ dst, int* __restrict__ deg) {
    int e = blockIdx.x * blockDim.x + threadIdx.x;
    if (e < N_EDGES) atomicAdd(&deg[dst[e]], 1);
}

__global__ __launch_bounds__(SCAN_B) void scanA_kernel(const int* __restrict__ deg,
                                                       int* __restrict__ incl,
                                                       int* __restrict__ partials) {
    __shared__ int tmp[SCAN_B];
    const int tid = threadIdx.x;
    const int i = blockIdx.x * SCAN_B + tid;
    int v = (i < N_NODES) ? deg[i] : 0;
    tmp[tid] = v;
    __syncthreads();
    for (int off = 1; off < SCAN_B; off <<= 1) {
        int t = (tid >= off) ? tmp[tid - off] : 0;
        __syncthreads();
        tmp[tid] += t;
        __syncthreads();
    }
    if (i < N_NODES) incl[i] = tmp[tid];
    if (tid == SCAN_B - 1) partials[blockIdx.x] = tmp[tid];
}

__global__ __launch_bounds__(64) void scanB_kernel(int* __restrict__ partials,
                                                   int* __restrict__ poff) {
    if (threadIdx.x == 0) {
        int run = 0;
        for (int b = 0; b < SCAN_NB; b++) {
            poff[b] = run;
            run += partials[b];
        }
        poff[SCAN_NB] = run;
    }
}

__global__ __launch_bounds__(SCAN_B) void scanC_kernel(const int* __restrict__ deg,
                                                       const int* __restrict__ incl,
                                                       const int* __restrict__ poff,
                                                       int* __restrict__ rowoff,
                                                       int* __restrict__ cursor) {
    const int i = blockIdx.x * SCAN_B + threadIdx.x;
    if (i >= N_NODES) return;
    const int excl = poff[blockIdx.x] + incl[i] - deg[i];
    rowoff[i] = excl;
    cursor[i] = excl;
    if (i == N_NODES - 1) rowoff[N_NODES] = poff[blockIdx.x] + incl[i];
}

__global__ void scatter_kernel(const int* __restrict__ src, const int* __restrict__ dst,
                               int* __restrict__ cursor, int* __restrict__ csr_src) {
    int e = blockIdx.x * blockDim.x + threadIdx.x;
    if (e >= N_EDGES) return;
    int d = dst[e];
    int pos = atomicAdd(&cursor[d], 1);
    csr_src[pos] = src[e];
}

// ---------------- layer-1 aggregation: 128 threads, thread = channel pair ----------------
__global__ __launch_bounds__(128) void agg1_kernel(
        const int* __restrict__ rowoff, const int* __restrict__ csr,
        const float* __restrict__ as_, const float* __restrict__ ad_,
        const ushort_t* __restrict__ hb, const float* __restrict__ bias,
        ushort_t* __restrict__ x2h, ushort_t* __restrict__ x2l) {
    const int n = blockIdx.x;
    const int tid = threadIdx.x;          // channel pair (2*tid, 2*tid+1)
    const int head = tid >> 6;
    __shared__ int s_src[128];
    __shared__ float s_w[2][128];
    const float adv0 = ad_[n * 2], adv1 = ad_[n * 2 + 1];
    const int r0 = rowoff[n], r1 = rowoff[n + 1];
    float acc0 = 0.f, acc1 = 0.f, wsum = 0.f;
    for (int base = r0; base < r1; base += 128) {
        const int cnt = min(128, r1 - base);
        __syncthreads();
        if (tid < cnt) {
            int s = csr[base + tid];
            s_src[tid] = s;
            const float2 a2 = *reinterpret_cast<const float2*>(as_ + s * 2);
            s_w[0][tid] = __expf(lrelu(a2.x + adv0));
            s_w[1][tid] = __expf(lrelu(a2.y + adv1));
        }
        __syncthreads();
#pragma unroll 4
        for (int j = 0; j < cnt; j++) {
            const float w = s_w[head][j];
            const unsigned v = *reinterpret_cast<const unsigned*>(
                hb + (size_t)s_src[j] * 256 + 2 * tid);
            acc0 += b2f((unsigned short)(v & 0xffffu)) * w;
            acc1 += b2f((unsigned short)(v >> 16)) * w;
            wsum += w;
        }
    }
    const float inv = 1.f / (wsum + 1e-16f);
    const float2 bv = *reinterpret_cast<const float2*>(bias + 2 * tid);
    float o0 = acc0 * inv + bv.x;
    float o1 = acc1 * inv + bv.y;
    o0 = (o0 > 0.f) ? o0 : (__expf(o0) - 1.f);
    o1 = (o1 > 0.f) ? o1 : (__expf(o1) - 1.f);
    ushort2 hh, ll;
    hh.x = f2b(o0); ll.x = f2b(o0 - b2f(hh.x));
    hh.y = f2b(o1); ll.y = f2b(o1 - b2f(hh.y));
    *reinterpret_cast<ushort2*>(x2h + (size_t)n * 256 + 2 * tid) = hh;
    *reinterpret_cast<ushort2*>(x2l + (size_t)n * 256 + 2 * tid) = ll;
}

// ---------------- layer-2 aggregation: wave per node, bf16 gather ----------------
__global__ __launch_bounds__(256) void agg2_kernel(
        const int* __restrict__ rowoff, const int* __restrict__ csr,
        const float* __restrict__ as_, const float* __restrict__ ad_,
        const ushort_t* __restrict__ h2b, const float* __restrict__ bias,
        float* __restrict__ out) {
    const int wid = threadIdx.x >> 6, lane = threadIdx.x & 63;
    const int n = blockIdx.x * 4 + wid;
    if (n >= N_NODES) return;
    const int c2 = lane & 31;
    const int half = lane >> 5;
    const float adv = ad_[n];
    const int r0 = rowoff[n], r1 = rowoff[n + 1];
    float acc0 = 0.f, acc1 = 0.f, wsum = 0.f;

    for (int base = r0; base < r1; base += 64) {
        const int cnt = min(64, r1 - base);
        int s = 0;
        float w = 0.f;
        if (lane < cnt) {
            s = csr[base + lane];
            w = __expf(lrelu(as_[s] + adv));
        }
        const int half_rounds = (cnt + 1) >> 1;
#pragma unroll 4
        for (int jj = 0; jj < half_rounds; jj++) {
            const int j = jj * 2 + half;
            const int sb = __shfl(s, j);
            const float wb = __shfl(w, j);
            if (j < cnt) {
                const unsigned v = *reinterpret_cast<const unsigned*>(
                    h2b + (size_t)sb * 64 + 2 * c2);
                acc0 += b2f((unsigned short)(v & 0xffffu)) * wb;
                acc1 += b2f((unsigned short)(v >> 16)) * wb;
                wsum += wb;
            }
        }
    }
    acc0 += __shfl_xor(acc0, 32);
    acc1 += __shfl_xor(acc1, 32);
    wsum += __shfl_xor(wsum, 32);
    if (half == 0) {
        const float inv = 1.f / (wsum + 1e-16f);
        float2 o;
        o.x = acc0 * inv + bias[2 * c2];
        o.y = acc1 * inv + bias[2 * c2 + 1];
        *reinterpret_cast<float2*>(out + (size_t)n * 64 + 2 * c2) = o;
    }
}

// ---------------- launch ----------------
extern "C" void kernel_launch(void* const* d_in, const int* in_sizes, int n_in,
                              void* d_out, int out_size, void* d_ws, size_t ws_size,
                              hipStream_t stream) {
    const float* x_paper  = (const float*)d_in[0];
    const float* x_author = (const float*)d_in[1];
    const int*   edge_idx = (const int*)d_in[2];
    const float* W1p = (const float*)d_in[3];
    const float* b1p = (const float*)d_in[4];
    const float* W1a = (const float*)d_in[5];
    const float* b1a = (const float*)d_in[6];
    const float* Wg1 = (const float*)d_in[7];
    const float* asrc1 = (const float*)d_in[8];
    const float* adst1 = (const float*)d_in[9];
    const float* bg1 = (const float*)d_in[10];
    const float* Wg2 = (const float*)d_in[11];
    const float* asrc2 = (const float*)d_in[12];
    const float* adst2 = (const float*)d_in[13];
    const float* bg2 = (const float*)d_in[14];
    float* out = (float*)d_out;

    const int* src = edge_idx;
    const int* dst = edge_idx + N_EDGES;

    char* ws = (char*)d_ws;
    size_t off = 0;
    auto alloc = [&](size_t bytes) -> void* {
        void* p = ws + off;
        off += (bytes + 255) & ~(size_t)255;
        return p;
    };
    ushort_t* xh    = (ushort_t*)alloc((size_t)N_NODES * N_HID * 2);
    ushort_t* xl    = (ushort_t*)alloc((size_t)N_NODES * N_HID * 2);
    ushort_t* h1b   = (ushort_t*)alloc((size_t)N_NODES * 2 * N_HID * 2);
    ushort_t* x2h   = (ushort_t*)alloc((size_t)N_NODES * 2 * N_HID * 2);
    ushort_t* x2l   = (ushort_t*)alloc((size_t)N_NODES * 2 * N_HID * 2);
    ushort_t* h2b   = (ushort_t*)alloc((size_t)N_NODES * N_OUT * 2);
    ushort_t* wt1ph = (ushort_t*)alloc((size_t)D_PAPER * N_HID * 2);
    ushort_t* wt1pl = (ushort_t*)alloc((size_t)D_PAPER * N_HID * 2);
    ushort_t* wt1ah = (ushort_t*)alloc((size_t)D_AUTHOR * N_HID * 2);
    ushort_t* wt1al = (ushort_t*)alloc((size_t)D_AUTHOR * N_HID * 2);
    ushort_t* wtg1h = (ushort_t*)alloc((size_t)N_HID * 2 * N_HID * 2);
    ushort_t* wtg1l = (ushort_t*)alloc((size_t)N_HID * 2 * N_HID * 2);
    ushort_t* wtg2h = (ushort_t*)alloc((size_t)2 * N_HID * N_OUT * 2);
    ushort_t* wtg2l = (ushort_t*)alloc((size_t)2 * N_HID * N_OUT * 2);
    float*    as1   = (float*)alloc((size_t)N_NODES * HEADS * 4);
    float*    ad1   = (float*)alloc((size_t)N_NODES * HEADS * 4);
    float*    as2   = (float*)alloc((size_t)N_NODES * 4);
    float*    ad2   = (float*)alloc((size_t)N_NODES * 4);
    int*      deg    = (int*)alloc((size_t)N_NODES * 4);
    int*      incl   = (int*)alloc((size_t)N_NODES * 4);
    int*      parts  = (int*)alloc((size_t)(SCAN_NB + 1) * 4);
    int*      poff   = (int*)alloc((size_t)(SCAN_NB + 1) * 4);
    int*      rowoff = (int*)alloc((size_t)(N_NODES + 1) * 4);
    int*      cursor = (int*)alloc((size_t)N_NODES * 4);
    int*      csrsrc = (int*)alloc((size_t)N_EDGES * 4);

    const int EB = (N_EDGES + 255) / 256;

    // --- W pre-split/transpose ---
    wsplit_all<<<576, 256, 0, stream>>>(W1p, W1a, Wg1, Wg2,
        wt1ph, wt1pl, wt1ah, wt1al, wtg1h, wtg1l, wtg2h, wtg2l);

    // --- CSR build (multi-block scan) ---
    hipMemsetAsync(deg, 0, N_NODES * 4, stream);
    deg_kernel<<<EB, 256, 0, stream>>>(dst, deg);
    scanA_kernel<<<SCAN_NB, SCAN_B, 0, stream>>>(deg, incl, parts);
    scanB_kernel<<<1, 64, 0, stream>>>(parts, poff);
    scanC_kernel<<<SCAN_NB, SCAN_B, 0, stream>>>(deg, incl, poff, rowoff, cursor);
    scatter_kernel<<<EB, 256, 0, stream>>>(src, dst, cursor, csrsrc);

    // --- encoders: fp32 in, split-bf16 out (RW=1: 64 rows/block for occupancy) ---
    gemm_mfma_kernel<8, 1, 0><<<dim3((N_PAPER + 63) / 64, 1), 256, 0, stream>>>(
        x_paper, nullptr, wt1ph, wt1pl, b1p, nullptr, nullptr,
        xh, xl, nullptr, nullptr, N_PAPER, D_PAPER, N_HID);
    gemm_mfma_kernel<8, 1, 0><<<dim3((N_AUTHOR + 63) / 64, 1), 256, 0, stream>>>(
        x_author, nullptr, wt1ah, wt1al, b1a, nullptr, nullptr,
        xh + (size_t)N_PAPER * N_HID, xl + (size_t)N_PAPER * N_HID,
        nullptr, nullptr, N_AUTHOR, D_AUTHOR, N_HID);

    // --- GAT layer 1: transform + fused alpha (RW=2: 128 rows/block) ---
    gemm_mfma_kernel<8, 2, 1><<<dim3((N_NODES + 127) / 128, 2), 256, 0, stream>>>(
        xh, xl, wtg1h, wtg1l, nullptr, asrc1, adst1,
        h1b, nullptr, as1, ad1, N_NODES, N_HID, 2 * N_HID);
    agg1_kernel<<<N_NODES, 128, 0, stream>>>(rowoff, csrsrc, as1, ad1, h1b, bg1, x2h, x2l);

    // --- GAT layer 2: transform + fused alpha (RW=2) ---
    gemm_mfma_kernel<4, 2, 2><<<dim3((N_NODES + 127) / 128, 1), 256, 0, stream>>>(
        x2h, x2l, wtg2h, wtg2l, nullptr, asrc2, adst2,
        h2b, nullptr, as2, ad2, N_NODES, 2 * N_HID, N_OUT);
    agg2_kernel<<<(N_NODES + 3) / 4, 256, 0, stream>>>(rowoff, csrsrc, as2, ad2, h2b, bg2, out);
}